// Round 3
// baseline (465.389 us; speedup 1.0000x reference)
//
#include <hip/hip_runtime.h>

// Contracter: out[z,u,k] = sum_{i,j} x1[z,u,i]*x2[z,u,j]*ww[u,k,i,j],
// ww[u,k,i,j] = sum_p weights[u,p]*w3j[p,k,i,j]. Z=50000, 64 channels, BASE=9.
//
// R1: lane=z, 1 u/wave, scalar dword access -> TCP transaction-bound:
//     27 instrs x 64 lines x 195 waves/CU = 140us (measured 144).
// R2: LDS staging -> latency/barrier-bound, 178us. Reverted.
// R3: lane=z, 4 consecutive u per wave (u0%4==0 -> 144B per-lane segment is
//     16B-aligned) -> all global access float4: 4x work per transaction,
//     TCP time ~35us. Coefficients packed path-major per u (363 floats) so
//     wave-uniform reads become sequential s_load_dwordx16. No LDS, no
//     barriers. Blocks (16-u range = 576B = 9 whole lines per z-row) share
//     no cache lines -> no swizzle needed.

#define MUL   64
#define BASE  9
#define NPATH 11
#define NC    363   // packed coefficients per channel
#define CPAD  368   // pad to 1472B (line-aligned rows)

// path tables: irrep index (0->l=0,1->l=1,2->l=2) for in1, in2, out
#define PATH_TABLES \
    constexpr int P1[NPATH] = {0,0,0,1,1,1,1,2,2,2,2}; \
    constexpr int P2[NPATH] = {0,1,2,0,1,1,2,0,1,2,2}; \
    constexpr int PO[NPATH] = {0,1,2,1,0,2,1,2,1,0,2}; \
    constexpr int NL[3]  = {1,3,5}; \
    constexpr int OFF[3] = {0,1,4};

// Fold per-channel path weights into a packed, path-major coefficient row:
// cw[u][idx], idx enumerating (p; i in n1; j in n2; k in no) in that order.
__global__ __launch_bounds__(384) void fold_pack_kernel(
    const float* __restrict__ weights,   // (64, 11)
    const float* __restrict__ w3j,       // (11, 9, 9, 9) as (p, k, i, j)
    float*       __restrict__ cw)        // (64, CPAD)
{
    PATH_TABLES
    constexpr int SZ[NPATH] = {1,9,25,9,9,45,45,25,45,25,125}; // n1*n2*no

    int u   = blockIdx.x;
    int idx = threadIdx.x;
    if (idx >= NC) return;

    int p = 0, rem = idx;
    while (rem >= SZ[p]) { rem -= SZ[p]; ++p; }
    int n2 = NL[P2[p]], no = NL[PO[p]];
    int i  = rem / (n2 * no);
    int r  = rem - i * (n2 * no);
    int j  = r / no;
    int k  = r - j * no;
    int gi = OFF[P1[p]] + i;
    int gj = OFF[P2[p]] + j;
    int gk = OFF[PO[p]] + k;

    cw[u * CPAD + idx] = weights[u * NPATH + p] * w3j[p * 729 + gk * 81 + gi * 9 + gj];
}

__global__ __launch_bounds__(256, 3) void tp_kernel(
    const float* __restrict__ x1,
    const float* __restrict__ x2,
    const float* __restrict__ cw,        // (64, CPAD) packed
    float*       __restrict__ out,
    int Z)
{
    PATH_TABLES

    int g    = blockIdx.x;               // zt*4 + grp
    int zt   = g >> 2;
    int grp  = g & 3;
    int wave = threadIdx.x >> 6;
    int lane = threadIdx.x & 63;

    int z    = zt * 64 + lane;
    bool act = (z < Z);
    int zc   = act ? z : (Z - 1);        // clamp: loads stay in-bounds, store masked

    // wave-uniform base channel, multiple of 4 -> 16B-aligned segments
    int u0 = __builtin_amdgcn_readfirstlane((grp * 4 + wave) * 4);

    const float4* a4 = (const float4*)(x1 + (size_t)zc * (MUL * BASE) + u0 * BASE);
    const float4* b4 = (const float4*)(x2 + (size_t)zc * (MUL * BASE) + u0 * BASE);

    float4 Av[9], Bv[9];                 // 36 floats each: channels u0..u0+3
#pragma unroll
    for (int i = 0; i < 9; ++i) { Av[i] = a4[i]; Bv[i] = b4[i]; }
    const float* X1 = (const float*)Av;
    const float* X2 = (const float*)Bv;

    float4 Ov[9];
    float* O = (float*)Ov;
#pragma unroll
    for (int k = 0; k < 36; ++k) O[k] = 0.f;

#pragma unroll
    for (int uu = 0; uu < 4; ++uu) {
        const float* __restrict__ cr = cw + (size_t)(u0 + uu) * CPAD; // uniform -> SMRD
        const float* xa = X1 + uu * BASE;
        const float* xb = X2 + uu * BASE;
        float*       oo = O  + uu * BASE;

        int c = 0;   // compile-time after full unroll; order matches fold_pack
#pragma unroll
        for (int p = 0; p < NPATH; ++p) {
            const int o1 = OFF[P1[p]], n1 = NL[P1[p]];
            const int o2 = OFF[P2[p]], n2 = NL[P2[p]];
            const int og = OFF[PO[p]], no = NL[PO[p]];
#pragma unroll
            for (int i = 0; i < n1; ++i) {
                float a = xa[o1 + i];
#pragma unroll
                for (int j = 0; j < n2; ++j) {
                    float rv = a * xb[o2 + j];
#pragma unroll
                    for (int k = 0; k < no; ++k) {
                        oo[og + k] = fmaf(cr[c], rv, oo[og + k]);
                        ++c;
                    }
                }
            }
        }
    }

    if (act) {
        float4* o4 = (float4*)(out + (size_t)z * (MUL * BASE) + u0 * BASE);
#pragma unroll
        for (int i = 0; i < 9; ++i) o4[i] = Ov[i];
    }
}

extern "C" void kernel_launch(void* const* d_in, const int* in_sizes, int n_in,
                              void* d_out, int out_size, void* d_ws, size_t ws_size,
                              hipStream_t stream) {
    const float* x1  = (const float*)d_in[0];
    const float* x2  = (const float*)d_in[1];
    const float* w   = (const float*)d_in[2];   // (64, 11)
    const float* w3j = (const float*)d_in[3];   // (11, 729)
    float* out = (float*)d_out;
    float* cw  = (float*)d_ws;                  // (64, CPAD) = 94KB scratch

    int Z = in_sizes[0] / (MUL * BASE);

    fold_pack_kernel<<<MUL, 384, 0, stream>>>(w, w3j, cw);

    int nzt  = (Z + 63) / 64;                   // 782
    int grid = nzt * 4;                         // 4 u-groups (16 u) per block
    tp_kernel<<<grid, 256, 0, stream>>>(x1, x2, cw, out, Z);
}